// Round 13
// baseline (1645.109 us; speedup 1.0000x reference)
//
#include <hip/hip_runtime.h>
#include <hip/hip_bf16.h>
#include <stdint.h>

typedef unsigned int u32;
typedef unsigned short u16;
typedef __attribute__((ext_vector_type(8))) short bf16x8;
typedef __attribute__((ext_vector_type(4))) float f32x4;

#define NTOK 32768
#define DDIM 1024
#define HDIM 4096
#define NEXP 8
#define MAXSLOTS 67584  // 65536 + 8*256 worst-case padded slots

#define BM 256
#define BN 128
#define BK 64
#define ABYTES 32768          // 256 x 64 bf16
#define BUFBYTES 49152        // A 32K + B 16K
#define LDSBYTES 147456       // 3 buffers

// hardware RNE f32->bf16
__device__ __forceinline__ u16 f2bf(float f) {
  __hip_bfloat16 h = __float2bfloat16(f);
  return __builtin_bit_cast(u16, h);
}
__device__ __forceinline__ float bf2f(u32 lo16) {
  return __builtin_bit_cast(float, lo16 << 16);
}

__device__ __forceinline__ void gload16(const void* g, void* l) {
  __builtin_amdgcn_global_load_lds((const __attribute__((address_space(1))) u32*)g,
                                   (__attribute__((address_space(3))) u32*)l, 16, 0, 0);
}

// ---------------- x fp32 -> bf16 ----------------
__global__ __launch_bounds__(256)
void k_cvt_x(const float* __restrict__ x, u16* __restrict__ xb, int n4) {
  int i = blockIdx.x * 256 + threadIdx.x;
  int stride = gridDim.x * 256;
  for (; i < n4; i += stride) {
    float4 v = ((const float4*)x)[i];
    u32 p0 = (u32)f2bf(v.x) | ((u32)f2bf(v.y) << 16);
    u32 p1 = (u32)f2bf(v.z) | ((u32)f2bf(v.w) << 16);
    ((uint2*)xb)[i] = make_uint2(p0, p1);
  }
}

// ------- W [E][R][C] fp32 -> WT [E][C][R] bf16 (tiled transpose, vectorized) -------
__global__ __launch_bounds__(256)
void k_transpose(const float* __restrict__ W, u16* __restrict__ WT, int R, int C) {
  __shared__ float tile[64][65];
  int tilesC = C >> 6;
  int tilesPerE = (R >> 6) * tilesC;
  int b = blockIdx.x;
  int e = b / tilesPerE;
  int rem = b % tilesPerE;
  int tr = rem / tilesC, tc = rem % tilesC;
  const float* src = W + (size_t)e * R * C + (size_t)(tr * 64) * C + tc * 64;
  int tid = threadIdx.x;
#pragma unroll
  for (int it = 0; it < 4; it++) {
    int idx = it * 256 + tid;
    int r = idx >> 4, c4 = (idx & 15) * 4;
    float4 v = *(const float4*)(src + (size_t)r * C + c4);
    tile[r][c4 + 0] = v.x; tile[r][c4 + 1] = v.y;
    tile[r][c4 + 2] = v.z; tile[r][c4 + 3] = v.w;
  }
  __syncthreads();
  u16* dst = WT + (size_t)e * R * C + (size_t)(tc * 64) * R + tr * 64;
#pragma unroll
  for (int it = 0; it < 4; it++) {
    int idx = it * 256 + tid;
    int cc = idx >> 4, r4 = (idx & 15) * 4;
    u32 p0 = (u32)f2bf(tile[r4 + 0][cc]) | ((u32)f2bf(tile[r4 + 1][cc]) << 16);
    u32 p1 = (u32)f2bf(tile[r4 + 2][cc]) | ((u32)f2bf(tile[r4 + 3][cc]) << 16);
    *(uint2*)(dst + (size_t)cc * R + r4) = make_uint2(p0, p1);
  }
}

// ---------------- router (proven): fp32 logits, top-2; 4 threads/token ----------------
__global__ __launch_bounds__(256)
void k_router(const float* __restrict__ x, const float* __restrict__ Wr,
              const float* __restrict__ br, int* __restrict__ tokPack,
              float* __restrict__ tokW, int* __restrict__ counts) {
  __shared__ float wl[DDIM * NEXP];   // 32 KB
  __shared__ int cnt[NEXP];
  int tid = threadIdx.x;
  if (tid < NEXP) cnt[tid] = 0;
  for (int i = tid; i < DDIM * NEXP / 4; i += 256)
    ((float4*)wl)[i] = ((const float4*)Wr)[i];
  __syncthreads();
  const int n = blockIdx.x * 64 + (tid >> 2);
  const int d0 = (tid & 3) * 256;
  float acc[8] = {0.f, 0.f, 0.f, 0.f, 0.f, 0.f, 0.f, 0.f};
  const float4* xr = (const float4*)(x + (size_t)n * DDIM + d0);
  const float4* wlv = (const float4*)wl;
  for (int i = 0; i < 64; i++) {
    float4 xv = xr[i];
#pragma unroll
    for (int j = 0; j < 4; j++) {
      float xs = (&xv.x)[j];
      float4 wa = wlv[(d0 + i * 4 + j) * 2 + 0];
      float4 wb = wlv[(d0 + i * 4 + j) * 2 + 1];
      acc[0] += xs * wa.x; acc[1] += xs * wa.y; acc[2] += xs * wa.z; acc[3] += xs * wa.w;
      acc[4] += xs * wb.x; acc[5] += xs * wb.y; acc[6] += xs * wb.z; acc[7] += xs * wb.w;
    }
  }
#pragma unroll
  for (int e = 0; e < 8; e++) {
    acc[e] += __shfl_xor(acc[e], 1);
    acc[e] += __shfl_xor(acc[e], 2);
  }
  if ((tid & 3) == 0) {
    float v0 = -3.0e38f, v1 = -3.0e38f;
    int i0 = 0, i1 = 0;
#pragma unroll
    for (int e = 0; e < 8; e++) {
      float v = acc[e] + br[e];
      if (v > v0) { v1 = v0; i1 = i0; v0 = v; i0 = e; }
      else if (v > v1) { v1 = v; i1 = e; }
    }
    float w0 = 1.0f / (1.0f + expf(v1 - v0));
    tokPack[n] = i0 | (i1 << 8);
    tokW[n] = w0;
    atomicAdd(&cnt[i0], 1);
    atomicAdd(&cnt[i1], 1);
  }
  __syncthreads();
  if (tid < NEXP) atomicAdd(&counts[tid], cnt[tid]);
}

// sched layout (ints): [0..7]=counts, [8..16]=padOff (padOff[8]=totalPadded), [17..24]=cursors
__global__ void k_sched(int* __restrict__ sched) {
  if (threadIdx.x == 0 && blockIdx.x == 0) {
    int* padOff = sched + 8;
    int acc = 0;
    for (int e = 0; e < 8; e++) {
      padOff[e] = acc;
      int c = sched[e];
      acc += ((c + 255) >> 8) << 8;   // pad to BM=256
    }
    padOff[8] = acc;
  }
}

// hierarchical scatter; slotTok packs token | (plane<<16); pad slots stay -1
__global__ __launch_bounds__(256)
void k_scatter(const int* __restrict__ tokPack, const float* __restrict__ tokW,
               int* __restrict__ sched, int* __restrict__ slotTok,
               float* __restrict__ slotW) {
  __shared__ int cnt[NEXP], base[NEXP];
  int tid = threadIdx.x;
  if (tid < NEXP) cnt[tid] = 0;
  __syncthreads();
  int n = blockIdx.x * 256 + tid;
  int p = tokPack[n];
  float w0 = tokW[n];
  int e0 = p & 255, e1 = p >> 8;
  int r0 = atomicAdd(&cnt[e0], 1);
  int r1 = atomicAdd(&cnt[e1], 1);
  __syncthreads();
  int* cursors = sched + 17;
  if (tid < NEXP) base[tid] = atomicAdd(&cursors[tid], cnt[tid]);
  __syncthreads();
  const int* padOff = sched + 8;
  int s0 = padOff[e0] + base[e0] + r0;
  slotTok[s0] = n;                // plane 0 (weight w0)
  slotW[s0] = w0;
  int s1 = padOff[e1] + base[e1] + r1;
  slotTok[s1] = n | (1 << 16);    // plane 1 (weight 1-w0)
  slotW[s1] = 1.0f - w0;
}

// ---------- grouped GEMM: R5/R9-PROVEN 3-buffer counted-vmcnt pipeline ----------
// 256x128 tile, BK=64, 8 waves (4M x 2N, 64x64 each), mfma 16x16x32 bf16.
// Measured 955 TF (R5: 566 GFLOP / 593 us) -- fastest structure of the session.
// MODE 0: up (silu -> Hbuf). MODE 1: down atomic fallback. MODE 2: down -> ybuf.
template<int MODE>
__device__ __forceinline__ void gemm_body(
    const u16* __restrict__ A, const u16* __restrict__ Bw,
    const float* __restrict__ bias, const int* __restrict__ slotTok,
    const float* __restrict__ slotW, const int* __restrict__ sched,
    u16* __restrict__ obuf, float* __restrict__ dout, int chunkBase, char* lds) {
  constexpr bool UP = (MODE == 0);
  constexpr int KLEN = UP ? DDIM : HDIM;
  constexpr int NLEN = UP ? HDIM : DDIM;
  constexpr int NTT = NLEN / BN;
  constexpr int NK = KLEN / BK;
  const int* padOff = sched + 8;
  const int totalPadded = padOff[8];
  // m204 bijective XCD-chunked swizzle (valid for ANY nwg)
  const int nwg = gridDim.x;
  const int b0 = blockIdx.x;
  const int xcd = b0 & 7, lid = b0 >> 3;
  const int q = nwg >> 3, r8 = nwg & 7;
  const int wg = (xcd < r8 ? xcd * (q + 1) : r8 * (q + 1) + (xcd - r8) * q) + lid;
  const int mLocal = wg / NTT;
  const int nt = wg % NTT;
  const int rowbase = chunkBase + mLocal * BM;
  if (rowbase >= totalPadded) return;
  int e = 0;
#pragma unroll
  for (int i = 0; i < NEXP; i++)
    if (rowbase >= padOff[i + 1]) e = i + 1;
  const int n0 = nt * BN;
  const u16* Be = Bw + (size_t)e * HDIM * DDIM + (size_t)n0 * KLEN;
  const int tid = threadIdx.x, lane = tid & 63, wid = tid >> 6;
  const int localBase = rowbase - chunkBase;

  // staging source pointers (pre-swizzled 16B chunk: sc = c ^ (r&7))
  const char* aPtr[4];
  const char* bPtr[2];
#pragma unroll
  for (int p = 0; p < 4; p++) {
    int u = p * 512 + tid;
    int r = u >> 3, c = u & 7, sc = c ^ (r & 7);
    if constexpr (UP) {
      const int tok = slotTok[rowbase + r] & 0x7fff;  // pad(-1)/plane bit -> valid row
      aPtr[p] = (const char*)(A + (size_t)tok * KLEN) + sc * 16;
    } else {
      aPtr[p] = (const char*)(A + (size_t)(localBase + r) * KLEN) + sc * 16;
    }
  }
#pragma unroll
  for (int p = 0; p < 2; p++) {
    int u = p * 512 + tid;
    int r = u >> 3, c = u & 7, sc = c ^ (r & 7);
    bPtr[p] = (const char*)(Be + (size_t)r * KLEN) + sc * 16;
  }

#define STAGE_A(w, kt)                                                         \
  {                                                                            \
    char* d = lds + (w) * BUFBYTES;                                            \
    const size_t ko = (size_t)(kt) * 128;                                      \
    _Pragma("unroll") for (int p = 0; p < 4; p++)                              \
        gload16(aPtr[p] + ko, d + p * 8192 + tid * 16);                        \
  }
#define STAGE_B(w, kt)                                                         \
  {                                                                            \
    char* d = lds + (w) * BUFBYTES + ABYTES;                                   \
    const size_t ko = (size_t)(kt) * 128;                                      \
    _Pragma("unroll") for (int p = 0; p < 2; p++)                              \
        gload16(bPtr[p] + ko, d + p * 8192 + tid * 16);                        \
  }

  // ds_read addressing: row&7 == lane&7 for all fragments (wm*64, mi*16 ≡ 0 mod 8)
  const int wm = wid >> 1, wn = wid & 1;
  const int aLB = (wm * 64 + (lane & 15)) * 128;
  const int bLB = ABYTES + (wn * 64 + (lane & 15)) * 128;
  const int ch0 = (((lane >> 4)) ^ (lane & 7)) * 16;
  const int ch1 = ((4 + (lane >> 4)) ^ (lane & 7)) * 16;

  f32x4 acc[4][4] = {};

  // prologue: stage tiles 0 and 1 (6 loads each)
  STAGE_A(0, 0); STAGE_B(0, 0);
  STAGE_A(1, 1); STAGE_B(1, 1);

  int cur = 0;
#pragma unroll 1
  for (int t = 0; t < NK; t++) {
    if (t == NK - 1) { asm volatile("s_waitcnt vmcnt(0)" ::: "memory"); }
    else             { asm volatile("s_waitcnt vmcnt(6)" ::: "memory"); }
    __builtin_amdgcn_s_barrier();
    __builtin_amdgcn_sched_barrier(0);
    const char* bA = lds + cur * BUFBYTES;
    int wbuf = cur + 2; if (wbuf >= 3) wbuf -= 3;
    // ---- phase A: read mi0-1 + all B frags; stage A of tile t+2; mfma mi0-1
    bf16x8 a0r[2][2], b0r[4][2];
#pragma unroll
    for (int mi = 0; mi < 2; mi++) {
      a0r[mi][0] = *(const bf16x8*)(bA + aLB + mi * 2048 + ch0);
      a0r[mi][1] = *(const bf16x8*)(bA + aLB + mi * 2048 + ch1);
    }
#pragma unroll
    for (int ni = 0; ni < 4; ni++) {
      b0r[ni][0] = *(const bf16x8*)(bA + bLB + ni * 2048 + ch0);
      b0r[ni][1] = *(const bf16x8*)(bA + bLB + ni * 2048 + ch1);
    }
    if (t + 2 < NK) STAGE_A(wbuf, t + 2);
    __builtin_amdgcn_s_barrier();
    __builtin_amdgcn_s_setprio(1);
#pragma unroll
    for (int ks = 0; ks < 2; ks++)
#pragma unroll
      for (int mi = 0; mi < 2; mi++)
#pragma unroll
        for (int ni = 0; ni < 4; ni++)
          acc[mi][ni] = __builtin_amdgcn_mfma_f32_16x16x32_bf16(
              a0r[mi][ks], b0r[ni][ks], acc[mi][ni], 0, 0, 0);
    __builtin_amdgcn_s_setprio(0);
    __builtin_amdgcn_s_barrier();
    // ---- phase B: read mi2-3; stage B of tile t+2; mfma mi2-3
    bf16x8 a1r[2][2];
#pragma unroll
    for (int mi = 0; mi < 2; mi++) {
      a1r[mi][0] = *(const bf16x8*)(bA + aLB + (mi + 2) * 2048 + ch0);
      a1r[mi][1] = *(const bf16x8*)(bA + aLB + (mi + 2) * 2048 + ch1);
    }
    if (t + 2 < NK) STAGE_B(wbuf, t + 2);
    __builtin_amdgcn_s_barrier();
    __builtin_amdgcn_s_setprio(1);
#pragma unroll
    for (int ks = 0; ks < 2; ks++)
#pragma unroll
      for (int mi = 0; mi < 2; mi++)
#pragma unroll
        for (int ni = 0; ni < 4; ni++)
          acc[mi + 2][ni] = __builtin_amdgcn_mfma_f32_16x16x32_bf16(
              a1r[mi][ks], b0r[ni][ks], acc[mi + 2][ni], 0, 0, 0);
    __builtin_amdgcn_s_setprio(0);
    __builtin_amdgcn_s_barrier();
    cur = cur + 1; if (cur >= 3) cur = 0;
  }
  __builtin_amdgcn_sched_barrier(0);
#undef STAGE_A
#undef STAGE_B

  if constexpr (MODE == 0 || MODE == 2) {
    // epilogue via LDS bounce (256x128 u16 = 64 KB) -> coalesced bf16x8 stores
    u16* ot = (u16*)lds;
#pragma unroll
    for (int ni = 0; ni < 4; ni++) {
      const int colit = wn * 64 + ni * 16 + (lane & 15);
      const float bv = bias[e * NLEN + n0 + colit];
#pragma unroll
      for (int mi = 0; mi < 4; mi++) {
        const int rowit = wm * 64 + mi * 16 + (lane >> 4) * 4;
#pragma unroll
        for (int r2 = 0; r2 < 4; r2++) {
          float v = acc[mi][ni][r2] + bv;
          if constexpr (MODE == 0) v = v / (1.0f + __expf(-v));  // silu
          ot[(rowit + r2) * 128 + colit] = f2bf(v);
        }
      }
    }
    __syncthreads();
#pragma unroll
    for (int rd = 0; rd < 8; rd++) {
      const int row = rd * 32 + (tid >> 4);
      bf16x8 v = *(const bf16x8*)(ot + row * 128 + (tid & 15) * 8);
      if constexpr (MODE == 0) {
        *(bf16x8*)(obuf + (size_t)(localBase + row) * HDIM + n0 + (tid & 15) * 8) = v;
      } else {
        const int sv = slotTok[rowbase + row];
        if (sv >= 0) {
          const int tok = sv & 0xffff, k = (sv >> 16) & 1;
          *(bf16x8*)(obuf + ((size_t)k * NTOK + tok) * DDIM + n0 + (tid & 15) * 8) = v;
        }
      }
    }
  } else {
    // MODE 1: w * (acc + b2) -> atomicAdd into out
#pragma unroll
    for (int mi = 0; mi < 4; mi++) {
#pragma unroll
      for (int r2 = 0; r2 < 4; r2++) {
        const int prow = rowbase + wm * 64 + mi * 16 + (lane >> 4) * 4 + r2;
        const float w = slotW[prow];
        const int sv = slotTok[prow];
        if (w != 0.0f && sv >= 0) {
          const int tok = sv & 0xffff;
#pragma unroll
          for (int ni = 0; ni < 4; ni++) {
            const int col = n0 + wn * 64 + ni * 16 + (lane & 15);
            const float y = acc[mi][ni][r2] + bias[e * DDIM + col];
            atomicAdd(dout + (size_t)tok * DDIM + col, w * y);
          }
        }
      }
    }
  }
}

__global__ __launch_bounds__(512, 2)
void k_gemm_up(const u16* __restrict__ A, const u16* __restrict__ Bw,
               const float* __restrict__ bias, const int* __restrict__ slotTok,
               const float* __restrict__ slotW, const int* __restrict__ sched,
               u16* __restrict__ obuf, float* __restrict__ dout, int chunkBase) {
  __shared__ char lds[LDSBYTES];
  gemm_body<0>(A, Bw, bias, slotTok, slotW, sched, obuf, dout, chunkBase, lds);
}

__global__ __launch_bounds__(512, 2)
void k_gemm_dn_a(const u16* __restrict__ A, const u16* __restrict__ Bw,
                 const float* __restrict__ bias, const int* __restrict__ slotTok,
                 const float* __restrict__ slotW, const int* __restrict__ sched,
                 u16* __restrict__ obuf, float* __restrict__ dout, int chunkBase) {
  __shared__ char lds[LDSBYTES];
  gemm_body<1>(A, Bw, bias, slotTok, slotW, sched, obuf, dout, chunkBase, lds);
}

__global__ __launch_bounds__(512, 2)
void k_gemm_dn_y(const u16* __restrict__ A, const u16* __restrict__ Bw,
                 const float* __restrict__ bias, const int* __restrict__ slotTok,
                 const float* __restrict__ slotW, const int* __restrict__ sched,
                 u16* __restrict__ obuf, float* __restrict__ dout, int chunkBase) {
  __shared__ char lds[LDSBYTES];
  gemm_body<2>(A, Bw, bias, slotTok, slotW, sched, obuf, dout, chunkBase, lds);
}

// ------- gather token-indexed y planes + residual gate + LayerNorm -------
__global__ __launch_bounds__(256)
void k_ln_gather(const float* __restrict__ x, const u16* __restrict__ ybuf,
                 const float* __restrict__ tokW, const float* __restrict__ gs,
                 const float* __restrict__ gamma, const float* __restrict__ beta,
                 float* __restrict__ out) {
  const int lane = threadIdx.x & 63;
  const int row = blockIdx.x * 4 + (threadIdx.x >> 6);
  const float g = gs[0];
  const float w0 = tokW[row], w1 = 1.0f - w0;
  const float4* xr = (const float4*)(x + (size_t)row * DDIM);
  const u16* y0 = ybuf + (size_t)row * DDIM;
  const u16* y1 = ybuf + (size_t)NTOK * DDIM + (size_t)row * DDIM;
  float4 z[4];
  float s = 0.f, sq = 0.f;
#pragma unroll
  for (int t = 0; t < 4; t++) {
    const int fi = t * 64 + lane;
    float4 xv = xr[fi];
    uint2 a = *(const uint2*)(y0 + fi * 4);
    uint2 b = *(const uint2*)(y1 + fi * 4);
    float y0v[4] = {bf2f(a.x & 0xffff), bf2f(a.x >> 16),
                    bf2f(a.y & 0xffff), bf2f(a.y >> 16)};
    float y1v[4] = {bf2f(b.x & 0xffff), bf2f(b.x >> 16),
                    bf2f(b.y & 0xffff), bf2f(b.y >> 16)};
    float4 zz;
    zz.x = xv.x + g * (w0 * y0v[0] + w1 * y1v[0]);
    zz.y = xv.y + g * (w0 * y0v[1] + w1 * y1v[1]);
    zz.z = xv.z + g * (w0 * y0v[2] + w1 * y1v[2]);
    zz.w = xv.w + g * (w0 * y0v[3] + w1 * y1v[3]);
    z[t] = zz;
    s += zz.x + zz.y + zz.z + zz.w;
    sq += zz.x * zz.x + zz.y * zz.y + zz.z * zz.z + zz.w * zz.w;
  }
#pragma unroll
  for (int m = 1; m < 64; m <<= 1) {
    s += __shfl_xor(s, m);
    sq += __shfl_xor(sq, m);
  }
  const float mu = s * (1.0f / 1024.0f);
  const float var = sq * (1.0f / 1024.0f) - mu * mu;
  const float rstd = rsqrtf(var + 1e-5f);
  float4* orow = (float4*)(out + (size_t)row * DDIM);
#pragma unroll
  for (int t = 0; t < 4; t++) {
    const int fi = t * 64 + lane;
    float4 gm = ((const float4*)gamma)[fi];
    float4 bt = ((const float4*)beta)[fi];
    float4 o;
    o.x = (z[t].x - mu) * rstd * gm.x + bt.x;
    o.y = (z[t].y - mu) * rstd * gm.y + bt.y;
    o.z = (z[t].z - mu) * rstd * gm.z + bt.z;
    o.w = (z[t].w - mu) * rstd * gm.w + bt.w;
    orow[fi] = o;
  }
}

// ---------------- residual gate + LayerNorm in place (atomic fallback) ----------------
__global__ __launch_bounds__(256)
void k_ln(const float* __restrict__ x, const float* __restrict__ gs,
          const float* __restrict__ gamma, const float* __restrict__ beta,
          float* __restrict__ out) {
  const int row = blockIdx.x, tid = threadIdx.x;
  const float g = gs[0];
  const float4* xr = (const float4*)(x + (size_t)row * DDIM);
  float4* orow = (float4*)(out + (size_t)row * DDIM);
  float4 xv = xr[tid];
  float4 av = orow[tid];
  float4 z;
  z.x = xv.x + g * av.x; z.y = xv.y + g * av.y;
  z.z = xv.z + g * av.z; z.w = xv.w + g * av.w;
  float s = z.x + z.y + z.z + z.w;
  float ss = z.x * z.x + z.y * z.y + z.z * z.z + z.w * z.w;
#pragma unroll
  for (int m = 1; m < 64; m <<= 1) {
    s += __shfl_xor(s, m);
    ss += __shfl_xor(ss, m);
  }
  __shared__ float sh[8];
  if ((tid & 63) == 0) {
    sh[(tid >> 6) * 2] = s;
    sh[(tid >> 6) * 2 + 1] = ss;
  }
  __syncthreads();
  s = sh[0] + sh[2] + sh[4] + sh[6];
  ss = sh[1] + sh[3] + sh[5] + sh[7];
  const float mu = s * (1.0f / 1024.0f);
  const float var = ss * (1.0f / 1024.0f) - mu * mu;
  const float rstd = rsqrtf(var + 1e-5f);
  float4 gm = ((const float4*)gamma)[tid];
  float4 bt = ((const float4*)beta)[tid];
  float4 o;
  o.x = (z.x - mu) * rstd * gm.x + bt.x;
  o.y = (z.y - mu) * rstd * gm.y + bt.y;
  o.z = (z.z - mu) * rstd * gm.z + bt.z;
  o.w = (z.w - mu) * rstd * gm.w + bt.w;
  orow[tid] = o;
}

extern "C" void kernel_launch(void* const* d_in, const int* in_sizes, int n_in,
                              void* d_out, int out_size, void* d_ws, size_t ws_size,
                              hipStream_t stream) {
  const float* x = (const float*)d_in[0];
  const float* Wr = (const float*)d_in[1];
  const float* br = (const float*)d_in[2];
  const float* W1 = (const float*)d_in[3];
  const float* b1 = (const float*)d_in[4];
  const float* W2 = (const float*)d_in[5];
  const float* b2 = (const float*)d_in[6];
  const float* gs = (const float*)d_in[7];
  const float* gamma = (const float*)d_in[8];
  const float* beta = (const float*)d_in[9];
  float* out = (float*)d_out;

  char* ws = (char*)d_ws;
  size_t off = 0;
  auto alloc = [&](size_t bytes) -> void* {
    void* p = ws + off;
    off += (bytes + 255) / 256 * 256;
    return p;
  };
  u16* xb = (u16*)alloc((size_t)NTOK * DDIM * 2);           // 64 MiB
  u16* W1T = (u16*)alloc((size_t)NEXP * HDIM * DDIM * 2);   // 64 MiB
  u16* W2T = (u16*)alloc((size_t)NEXP * HDIM * DDIM * 2);   // 64 MiB
  int* tokPack = (int*)alloc((size_t)NTOK * 4);
  float* tokW = (float*)alloc((size_t)NTOK * 4);
  int* slotTok = (int*)alloc((size_t)MAXSLOTS * 4);
  float* slotW = (float*)alloc((size_t)MAXSLOTS * 4);
  int* sched = (int*)alloc(128 * 4);
  size_t offFixed = off;

  // Try ybuf path: dedicated [2][NTOK][DDIM] bf16 (128 MiB) + chunked Hbuf.
  u16* ybuf = (u16*)alloc((size_t)2 * NTOK * DDIM * 2);
  long long chv = ws_size > off ? (long long)((ws_size - off) / ((size_t)HDIM * 2)) : 0;
  int CHmax = (int)((chv / 256) * 256);
  if (CHmax > MAXSLOTS) CHmax = MAXSLOTS;
  bool yb = (CHmax >= 256);
  int CH;
  if (yb) {
    int nch0 = (MAXSLOTS + CHmax - 1) / CHmax;
    CH = (((MAXSLOTS + nch0 - 1) / nch0) + 255) / 256 * 256;  // balanced chunks
    if (CH > CHmax) CH = CHmax;
  } else {
    off = offFixed;
    ybuf = nullptr;
    chv = ws_size > off ? (long long)((ws_size - off) / ((size_t)HDIM * 2)) : 0;
    CH = (int)((chv / 256) * 256);
    if (CH > MAXSLOTS) CH = MAXSLOTS;
    if (CH < 256) CH = 256;
  }
  u16* Hbuf = (u16*)alloc((size_t)CH * HDIM * 2);
  int nch = (MAXSLOTS + CH - 1) / CH;

  if (!yb) hipMemsetAsync(d_out, 0, (size_t)out_size * 4, stream);
  hipMemsetAsync(slotTok, 0xFF, (size_t)MAXSLOTS * 4, stream);
  hipMemsetAsync(slotW, 0, (size_t)((char*)sched + 512 - (char*)slotW), stream);

  k_cvt_x<<<2048, 256, 0, stream>>>(x, xb, NTOK * DDIM / 4);
  k_transpose<<<NEXP * (DDIM / 64) * (HDIM / 64), 256, 0, stream>>>(W1, W1T, DDIM, HDIM);
  k_transpose<<<NEXP * (HDIM / 64) * (DDIM / 64), 256, 0, stream>>>(W2, W2T, HDIM, DDIM);
  k_router<<<NTOK / 64, 256, 0, stream>>>(x, Wr, br, tokPack, tokW, sched);
  k_sched<<<1, 64, 0, stream>>>(sched);
  k_scatter<<<NTOK / 256, 256, 0, stream>>>(tokPack, tokW, sched, slotTok, slotW);
  for (int c = 0; c < nch; c++) {
    k_gemm_up<<<(CH / BM) * (HDIM / BN), 512, 0, stream>>>(
        xb, W1T, b1, slotTok, slotW, sched, Hbuf, out, c * CH);
    if (yb) {
      k_gemm_dn_y<<<(CH / BM) * (DDIM / BN), 512, 0, stream>>>(
          Hbuf, W2T, b2, slotTok, slotW, sched, ybuf, out, c * CH);
    } else {
      k_gemm_dn_a<<<(CH / BM) * (DDIM / BN), 512, 0, stream>>>(
          Hbuf, W2T, b2, slotTok, slotW, sched, Hbuf, out, c * CH);
    }
  }
  if (yb) {
    k_ln_gather<<<NTOK / 4, 256, 0, stream>>>(x, ybuf, tokW, gs, gamma, beta, out);
  } else {
    k_ln<<<NTOK, 256, 0, stream>>>(x, gs, gamma, beta, out);
  }
}

// Round 14
// 1492.170 us; speedup vs baseline: 1.1025x; 1.1025x over previous
//
#include <hip/hip_runtime.h>
#include <stdint.h>

typedef unsigned int u32;
typedef unsigned short u16;
typedef __attribute__((ext_vector_type(8))) short bf16x8;
typedef __attribute__((ext_vector_type(4))) float f32x4;

#define NTOK 32768
#define DDIM 1024
#define HDIM 4096
#define NEXP 8
#define MAXSLOTS 67584  // 65536 + 8*256 worst-case padded slots

#define BM 256
#define BN 256
#define BK 64
#define BOFF 32768            // A tile 256x64 bf16 = 32 KB
#define BUFB 65536            // A + B per buffer
#define LDSBYTES 131072       // 2 buffers

#define SB() __builtin_amdgcn_sched_barrier(0)

__device__ __forceinline__ u16 f2bf(float f) {
  u32 u = __builtin_bit_cast(u32, f);
  u = (u + 0x7fff + ((u >> 16) & 1)) >> 16;   // round-to-nearest-even
  return (u16)u;
}
__device__ __forceinline__ float bf2f(u32 lo16) {
  return __builtin_bit_cast(float, lo16 << 16);
}

__device__ __forceinline__ void gload16(const void* g, void* l) {
  __builtin_amdgcn_global_load_lds((const __attribute__((address_space(1))) u32*)g,
                                   (__attribute__((address_space(3))) u32*)l, 16, 0, 0);
}

// ---------------- x fp32 -> bf16 ----------------
__global__ __launch_bounds__(256)
void k_cvt_x(const float* __restrict__ x, u16* __restrict__ xb, int n4) {
  int i = blockIdx.x * 256 + threadIdx.x;
  int stride = gridDim.x * 256;
  for (; i < n4; i += stride) {
    float4 v = ((const float4*)x)[i];
    u32 p0 = (u32)f2bf(v.x) | ((u32)f2bf(v.y) << 16);
    u32 p1 = (u32)f2bf(v.z) | ((u32)f2bf(v.w) << 16);
    ((uint2*)xb)[i] = make_uint2(p0, p1);
  }
}

// ------- W [E][R][C] fp32 -> WT [E][C][R] bf16 (tiled transpose, vectorized) -------
__global__ __launch_bounds__(256)
void k_transpose(const float* __restrict__ W, u16* __restrict__ WT, int R, int C) {
  __shared__ float tile[64][65];
  int tilesC = C >> 6;
  int tilesPerE = (R >> 6) * tilesC;
  int b = blockIdx.x;
  int e = b / tilesPerE;
  int rem = b % tilesPerE;
  int tr = rem / tilesC, tc = rem % tilesC;
  const float* src = W + (size_t)e * R * C + (size_t)(tr * 64) * C + tc * 64;
  int tid = threadIdx.x;
#pragma unroll
  for (int it = 0; it < 4; it++) {
    int idx = it * 256 + tid;
    int r = idx >> 4, c4 = (idx & 15) * 4;
    float4 v = *(const float4*)(src + (size_t)r * C + c4);
    tile[r][c4 + 0] = v.x; tile[r][c4 + 1] = v.y;
    tile[r][c4 + 2] = v.z; tile[r][c4 + 3] = v.w;
  }
  __syncthreads();
  u16* dst = WT + (size_t)e * R * C + (size_t)(tc * 64) * R + tr * 64;
#pragma unroll
  for (int it = 0; it < 4; it++) {
    int idx = it * 256 + tid;
    int cc = idx >> 4, r4 = (idx & 15) * 4;
    u32 p0 = (u32)f2bf(tile[r4 + 0][cc]) | ((u32)f2bf(tile[r4 + 1][cc]) << 16);
    u32 p1 = (u32)f2bf(tile[r4 + 2][cc]) | ((u32)f2bf(tile[r4 + 3][cc]) << 16);
    *(uint2*)(dst + (size_t)cc * R + r4) = make_uint2(p0, p1);
  }
}

// ---------------- router (proven): fp32 logits, top-2; 4 threads/token ----------------
__global__ __launch_bounds__(256)
void k_router(const float* __restrict__ x, const float* __restrict__ Wr,
              const float* __restrict__ br, int* __restrict__ tokPack,
              float* __restrict__ tokW, int* __restrict__ counts) {
  __shared__ float wl[DDIM * NEXP];   // 32 KB
  __shared__ int cnt[NEXP];
  int tid = threadIdx.x;
  if (tid < NEXP) cnt[tid] = 0;
  for (int i = tid; i < DDIM * NEXP / 4; i += 256)
    ((float4*)wl)[i] = ((const float4*)Wr)[i];
  __syncthreads();
  const int n = blockIdx.x * 64 + (tid >> 2);
  const int d0 = (tid & 3) * 256;
  float acc[8] = {0.f, 0.f, 0.f, 0.f, 0.f, 0.f, 0.f, 0.f};
  const float4* xr = (const float4*)(x + (size_t)n * DDIM + d0);
  const float4* wlv = (const float4*)wl;
  for (int i = 0; i < 64; i++) {
    float4 xv = xr[i];
#pragma unroll
    for (int j = 0; j < 4; j++) {
      float xs = (&xv.x)[j];
      float4 wa = wlv[(d0 + i * 4 + j) * 2 + 0];
      float4 wb = wlv[(d0 + i * 4 + j) * 2 + 1];
      acc[0] += xs * wa.x; acc[1] += xs * wa.y; acc[2] += xs * wa.z; acc[3] += xs * wa.w;
      acc[4] += xs * wb.x; acc[5] += xs * wb.y; acc[6] += xs * wb.z; acc[7] += xs * wb.w;
    }
  }
#pragma unroll
  for (int e = 0; e < 8; e++) {
    acc[e] += __shfl_xor(acc[e], 1);
    acc[e] += __shfl_xor(acc[e], 2);
  }
  if ((tid & 3) == 0) {
    float v0 = -3.0e38f, v1 = -3.0e38f;
    int i0 = 0, i1 = 0;
#pragma unroll
    for (int e = 0; e < 8; e++) {
      float v = acc[e] + br[e];
      if (v > v0) { v1 = v0; i1 = i0; v0 = v; i0 = e; }
      else if (v > v1) { v1 = v; i1 = e; }
    }
    float w0 = 1.0f / (1.0f + expf(v1 - v0));
    tokPack[n] = i0 | (i1 << 8);
    tokW[n] = w0;
    atomicAdd(&cnt[i0], 1);
    atomicAdd(&cnt[i1], 1);
  }
  __syncthreads();
  if (tid < NEXP) atomicAdd(&counts[tid], cnt[tid]);
}

// sched layout (ints): [0..7]=counts, [8..16]=padOff (padOff[8]=totalPadded), [17..24]=cursors
__global__ void k_sched(int* __restrict__ sched) {
  if (threadIdx.x == 0 && blockIdx.x == 0) {
    int* padOff = sched + 8;
    int acc = 0;
    for (int e = 0; e < 8; e++) {
      padOff[e] = acc;
      int c = sched[e];
      acc += ((c + 255) >> 8) << 8;   // pad to BM=256
    }
    padOff[8] = acc;
  }
}

// hierarchical scatter; slotTok packs token | (plane<<16); pad slots stay -1
__global__ __launch_bounds__(256)
void k_scatter(const int* __restrict__ tokPack, const float* __restrict__ tokW,
               int* __restrict__ sched, int* __restrict__ slotTok,
               float* __restrict__ slotW) {
  __shared__ int cnt[NEXP], base[NEXP];
  int tid = threadIdx.x;
  if (tid < NEXP) cnt[tid] = 0;
  __syncthreads();
  int n = blockIdx.x * 256 + tid;
  int p = tokPack[n];
  float w0 = tokW[n];
  int e0 = p & 255, e1 = p >> 8;
  int r0 = atomicAdd(&cnt[e0], 1);
  int r1 = atomicAdd(&cnt[e1], 1);
  __syncthreads();
  int* cursors = sched + 17;
  if (tid < NEXP) base[tid] = atomicAdd(&cursors[tid], cnt[tid]);
  __syncthreads();
  const int* padOff = sched + 8;
  int s0 = padOff[e0] + base[e0] + r0;
  slotTok[s0] = n;                // plane 0 (weight w0)
  slotW[s0] = w0;
  int s1 = padOff[e1] + base[e1] + r1;
  slotTok[s1] = n | (1 << 16);    // plane 1 (weight 1-w0)
  slotW[s1] = 1.0f - w0;
}

// ------------- grouped GEMM: 256x256 tile, 8 waves of 128x64, BK=64 -------------
// m201-style 8-phase schedule, 2 K-tiles/iter (R11 config: SB-bracketed barriers,
// counted vmcnt(4) only at ph4/ph8, bijective XCD swizzle). Session-best structure
// (724 TF measured). MODE 0: up (silu->Hbuf). MODE 1: down atomic. MODE 2: down->ybuf.
template<int MODE>
__device__ __forceinline__ void gemm_body(
    const u16* __restrict__ A, const u16* __restrict__ Bw,
    const float* __restrict__ bias, const int* __restrict__ slotTok,
    const float* __restrict__ slotW, const int* __restrict__ sched,
    u16* __restrict__ obuf, float* __restrict__ dout, int chunkBase, char* lds) {
  constexpr bool UP = (MODE == 0);
  constexpr int KLEN = UP ? DDIM : HDIM;
  constexpr int NLEN = UP ? HDIM : DDIM;
  constexpr int NTT = NLEN / BN;
  constexpr int NK = KLEN / BK;
  const int* padOff = sched + 8;
  const int totalPadded = padOff[8];
  // m204 bijective XCD-chunked swizzle (valid for ANY nwg)
  const int nwg = gridDim.x;
  const int b0 = blockIdx.x;
  const int xcd = b0 & 7, lid = b0 >> 3;
  const int q = nwg >> 3, r8 = nwg & 7;
  const int wg = (xcd < r8 ? xcd * (q + 1) : r8 * (q + 1) + (xcd - r8) * q) + lid;
  const int mLocal = wg / NTT;
  const int nt = wg % NTT;
  const int rowbase = chunkBase + mLocal * BM;
  if (rowbase >= totalPadded) return;
  int e = 0;
#pragma unroll
  for (int i = 0; i < NEXP; i++)
    if (rowbase >= padOff[i + 1]) e = i + 1;
  const int n0 = nt * BN;
  const u16* Be = Bw + (size_t)e * HDIM * DDIM + (size_t)n0 * KLEN;
  const int tid = threadIdx.x, lane = tid & 63, wid = tid >> 6;
  const int localBase = rowbase - chunkBase;

  // staging sources, pre-swizzled chunk: sc = c ^ (r&7)
  const char* aPtr[4];
  const char* bPtr[4];
#pragma unroll
  for (int p = 0; p < 4; p++) {
    int u = p * 512 + tid;
    int r = u >> 3, c = u & 7, sc = c ^ (r & 7);
    if constexpr (UP) {
      const int tok = slotTok[rowbase + r] & 0x7fff;  // pad(-1)/plane bit -> valid row
      aPtr[p] = (const char*)(A + (size_t)tok * KLEN) + sc * 16;
    } else {
      aPtr[p] = (const char*)(A + (size_t)(localBase + r) * KLEN) + sc * 16;
    }
    bPtr[p] = (const char*)(Be + (size_t)r * KLEN) + sc * 16;
  }

// stage one half-tile (2 gload_lds per thread); h=0: rows 0-127, h=1: rows 128-255
#define STAGE_HA(buf, h, kt)                                                   \
  {                                                                            \
    char* d = lds + (buf) * BUFB;                                              \
    const size_t ko = (size_t)(kt) * 128;                                      \
    gload16(aPtr[2 * (h)] + ko, d + ((2 * (h)) * 512 + tid) * 16);             \
    gload16(aPtr[2 * (h) + 1] + ko, d + ((2 * (h) + 1) * 512 + tid) * 16);     \
  }
#define STAGE_HB(buf, h, kt)                                                   \
  {                                                                            \
    char* d = lds + (buf) * BUFB + BOFF;                                       \
    const size_t ko = (size_t)(kt) * 128;                                      \
    gload16(bPtr[2 * (h)] + ko, d + ((2 * (h)) * 512 + tid) * 16);             \
    gload16(bPtr[2 * (h) + 1] + ko, d + ((2 * (h) + 1) * 512 + tid) * 16);     \
  }

  // 8 waves = 2 wm x 4 wn; per-wave out 128x64
  const int wm = wid >> 2, wn = wid & 3;
  const int aBase = (wm * 128 + (lane & 15)) * 128;
  const int bBase = BOFF + (wn * 64 + (lane & 15)) * 128;
  const int ch0 = (((lane >> 4)) ^ (lane & 7)) * 16;
  const int ch1 = ((4 + (lane >> 4)) ^ (lane & 7)) * 16;

  f32x4 acc[8][4] = {};

#define READ_B(bb)                                                             \
  _Pragma("unroll") for (int ni = 0; ni < 4; ni++) {                           \
    Bfr[ni][0] = *(const bf16x8*)((bb) + bBase + ni * 2048 + ch0);             \
    Bfr[ni][1] = *(const bf16x8*)((bb) + bBase + ni * 2048 + ch1);             \
  }
#define READ_A(bb, p)                                                          \
  _Pragma("unroll") for (int j = 0; j < 2; j++) {                              \
    Af[j][0] = *(const bf16x8*)((bb) + aBase + (2 * (p) + j) * 2048 + ch0);    \
    Af[j][1] = *(const bf16x8*)((bb) + aBase + (2 * (p) + j) * 2048 + ch1);    \
  }
#define MFMA16(p)                                                              \
  __builtin_amdgcn_s_setprio(1);                                               \
  _Pragma("unroll") for (int ks = 0; ks < 2; ks++)                             \
      _Pragma("unroll") for (int j = 0; j < 2; j++)                            \
          _Pragma("unroll") for (int ni = 0; ni < 4; ni++)                     \
              acc[2 * (p) + j][ni] = __builtin_amdgcn_mfma_f32_16x16x32_bf16(  \
                  Af[j][ks], Bfr[ni][ks], acc[2 * (p) + j][ni], 0, 0, 0);      \
  __builtin_amdgcn_s_setprio(0);
#define PHASE_MID()                                                            \
  SB();                                                                        \
  __builtin_amdgcn_s_barrier();                                                \
  asm volatile("s_waitcnt lgkmcnt(0)" ::: "memory");                           \
  SB();
#define BAR()                                                                  \
  SB();                                                                        \
  __builtin_amdgcn_s_barrier();                                                \
  SB();

  // prologue: A(t0), B(t0), B(t1) = 12 loads; drain all but B(t1)
  STAGE_HA(0, 0, 0); STAGE_HA(0, 1, 0);
  STAGE_HB(0, 0, 0); STAGE_HB(0, 1, 0);
  STAGE_HB(1, 0, 1); STAGE_HB(1, 1, 1);
  SB();
  asm volatile("s_waitcnt vmcnt(4)" ::: "memory");
  BAR();

  const char* bufA = lds;          // dbuf0: even tiles
  const char* bufB = lds + BUFB;   // dbuf1: odd tiles
#pragma unroll 1
  for (int i = 0; i < NK / 2; i++) {
    const int t1 = 2 * i + 1, t2 = 2 * i + 2, t3 = 2 * i + 3;
    bf16x8 Bfr[4][2], Af[2][2];
    // ---- ph1: B-all + A mi0-1 of even tile; stage A0(t1)->dbuf1
    READ_B(bufA); READ_A(bufA, 0);
    STAGE_HA(1, 0, t1);
    PHASE_MID(); MFMA16(0); BAR();
    // ---- ph2: A mi2-3; stage A1(t1)
    READ_A(bufA, 1);
    STAGE_HA(1, 1, t1);
    PHASE_MID(); MFMA16(1); BAR();
    // ---- ph3: A mi4-5; stage B0(t2)->dbuf0 (dbuf0.B free after ph1)
    READ_A(bufA, 2);
    if (t2 < NK) STAGE_HB(0, 0, t2);
    PHASE_MID(); MFMA16(2); BAR();
    // ---- ph4: A mi6-7; stage B1(t2); end: counted drain for ph5's reads
    READ_A(bufA, 3);
    if (t2 < NK) STAGE_HB(0, 1, t2);
    PHASE_MID(); MFMA16(3);
    SB();
    if (t2 < NK) { asm volatile("s_waitcnt vmcnt(4)" ::: "memory"); }
    else         { asm volatile("s_waitcnt vmcnt(0)" ::: "memory"); }
    __builtin_amdgcn_s_barrier();
    SB();
    // ---- ph5: B-all + A mi0-1 of odd tile; stage A0(t2)->dbuf0 (A free after ph4)
    READ_B(bufB); READ_A(bufB, 0);
    if (t2 < NK) STAGE_HA(0, 0, t2);
    PHASE_MID(); MFMA16(0); BAR();
    // ---- ph6: A mi2-3; stage A1(t2)
    READ_A(bufB, 1);
    if (t2 < NK) STAGE_HA(0, 1, t2);
    PHASE_MID(); MFMA16(1); BAR();
    // ---- ph7: A mi4-5; stage B0(t3)->dbuf1 (dbuf1.B free after ph5)
    READ_A(bufB, 2);
    if (t3 < NK) STAGE_HB(1, 0, t3);
    PHASE_MID(); MFMA16(2); BAR();
    // ---- ph8: A mi6-7; stage B1(t3); end: counted drain for next ph1's reads
    READ_A(bufB, 3);
    if (t3 < NK) STAGE_HB(1, 1, t3);
    PHASE_MID(); MFMA16(3);
    SB();
    if (i + 1 < NK / 2) { asm volatile("s_waitcnt vmcnt(4)" ::: "memory"); }
    else                { asm volatile("s_waitcnt vmcnt(0)" ::: "memory"); }
    __builtin_amdgcn_s_barrier();
    SB();
  }
#undef STAGE_HA
#undef STAGE_HB
#undef READ_B
#undef READ_A
#undef MFMA16
#undef PHASE_MID
#undef BAR

  if constexpr (MODE == 0 || MODE == 2) {
    // bounce 256x256 u16 tile (128 KB, XOR-swizzled rows) -> coalesced 16B stores
    __syncthreads();
#pragma unroll
    for (int ni = 0; ni < 4; ni++) {
      const int colit = wn * 64 + ni * 16 + (lane & 15);
      const float bv = bias[e * NLEN + n0 + colit];
#pragma unroll
      for (int mi = 0; mi < 8; mi++) {
#pragma unroll
        for (int r2 = 0; r2 < 4; r2++) {
          const int rowE = wm * 128 + mi * 16 + (lane >> 4) * 4 + r2;
          float v = acc[mi][ni][r2] + bv;
          if constexpr (MODE == 0) v = v / (1.0f + __expf(-v));  // silu
          const int byte = rowE * 512 + ((colit * 2) ^ ((rowE & 7) << 4));
          *(u16*)(lds + byte) = f2bf(v);
        }
      }
    }
    __syncthreads();
#pragma unroll
    for (int pass = 0; pass < 16; pass++) {
      const int row = pass * 16 + (tid >> 5);
      const int c = tid & 31;
      bf16x8 v = *(const bf16x8*)(lds + row * 512 + ((c * 16) ^ ((row & 7) << 4)));
      if constexpr (MODE == 0) {
        *(bf16x8*)(obuf + (size_t)(localBase + row) * HDIM + n0 + c * 8) = v;
      } else {
        const int sv = slotTok[rowbase + row];
        if (sv >= 0) {
          const int tok = sv & 0xffff, k = (sv >> 16) & 1;
          *(bf16x8*)(obuf + ((size_t)k * NTOK + tok) * DDIM + n0 + c * 8) = v;
        }
      }
    }
  } else {
    // MODE 1: atomic fallback
#pragma unroll
    for (int mi = 0; mi < 8; mi++) {
#pragma unroll
      for (int r2 = 0; r2 < 4; r2++) {
        const int prow = rowbase + wm * 128 + mi * 16 + (lane >> 4) * 4 + r2;
        const float w = slotW[prow];
        const int sv = slotTok[prow];
        if (w != 0.0f && sv >= 0) {
          const int tok = sv & 0xffff;
#pragma unroll
          for (int ni = 0; ni < 4; ni++) {
            const int col = n0 + wn * 64 + ni * 16 + (lane & 15);
            const float y = acc[mi][ni][r2] + bias[e * DDIM + col];
            atomicAdd(dout + (size_t)tok * DDIM + col, w * y);
          }
        }
      }
    }
  }
}

__global__ __launch_bounds__(512, 1)
void k_gemm_up(const u16* __restrict__ A, const u16* __restrict__ Bw,
               const float* __restrict__ bias, const int* __restrict__ slotTok,
               const float* __restrict__ slotW, const int* __restrict__ sched,
               u16* __restrict__ obuf, float* __restrict__ dout, int chunkBase) {
  __shared__ char lds[LDSBYTES];
  gemm_body<0>(A, Bw, bias, slotTok, slotW, sched, obuf, dout, chunkBase, lds);
}

__global__ __launch_bounds__(512, 1)
void k_gemm_dn_a(const u16* __restrict__ A, const u16* __restrict__ Bw,
                 const float* __restrict__ bias, const int* __restrict__ slotTok,
                 const float* __restrict__ slotW, const int* __restrict__ sched,
                 u16* __restrict__ obuf, float* __restrict__ dout, int chunkBase) {
  __shared__ char lds[LDSBYTES];
  gemm_body<1>(A, Bw, bias, slotTok, slotW, sched, obuf, dout, chunkBase, lds);
}

__global__ __launch_bounds__(512, 1)
void k_gemm_dn_y(const u16* __restrict__ A, const u16* __restrict__ Bw,
                 const float* __restrict__ bias, const int* __restrict__ slotTok,
                 const float* __restrict__ slotW, const int* __restrict__ sched,
                 u16* __restrict__ obuf, float* __restrict__ dout, int chunkBase) {
  __shared__ char lds[LDSBYTES];
  gemm_body<2>(A, Bw, bias, slotTok, slotW, sched, obuf, dout, chunkBase, lds);
}

// ------- gather token-indexed y planes + residual gate + LayerNorm -------
__global__ __launch_bounds__(256)
void k_ln_gather(const float* __restrict__ x, const u16* __restrict__ ybuf,
                 const float* __restrict__ tokW, const float* __restrict__ gs,
                 const float* __restrict__ gamma, const float* __restrict__ beta,
                 float* __restrict__ out) {
  const int lane = threadIdx.x & 63;
  const int row = blockIdx.x * 4 + (threadIdx.x >> 6);
  const float g = gs[0];
  const float w0 = tokW[row], w1 = 1.0f - w0;
  const float4* xr = (const float4*)(x + (size_t)row * DDIM);
  const u16* y0 = ybuf + (size_t)row * DDIM;
  const u16* y1 = ybuf + (size_t)NTOK * DDIM + (size_t)row * DDIM;
  float4 z[4];
  float s = 0.f, sq = 0.f;
#pragma unroll
  for (int t = 0; t < 4; t++) {
    const int fi = t * 64 + lane;
    float4 xv = xr[fi];
    uint2 a = *(const uint2*)(y0 + fi * 4);
    uint2 b = *(const uint2*)(y1 + fi * 4);
    float y0v[4] = {bf2f(a.x & 0xffff), bf2f(a.x >> 16),
                    bf2f(a.y & 0xffff), bf2f(a.y >> 16)};
    float y1v[4] = {bf2f(b.x & 0xffff), bf2f(b.x >> 16),
                    bf2f(b.y & 0xffff), bf2f(b.y >> 16)};
    float4 zz;
    zz.x = xv.x + g * (w0 * y0v[0] + w1 * y1v[0]);
    zz.y = xv.y + g * (w0 * y0v[1] + w1 * y1v[1]);
    zz.z = xv.z + g * (w0 * y0v[2] + w1 * y1v[2]);
    zz.w = xv.w + g * (w0 * y0v[3] + w1 * y1v[3]);
    z[t] = zz;
    s += zz.x + zz.y + zz.z + zz.w;
    sq += zz.x * zz.x + zz.y * zz.y + zz.z * zz.z + zz.w * zz.w;
  }
#pragma unroll
  for (int m = 1; m < 64; m <<= 1) {
    s += __shfl_xor(s, m);
    sq += __shfl_xor(sq, m);
  }
  const float mu = s * (1.0f / 1024.0f);
  const float var = sq * (1.0f / 1024.0f) - mu * mu;
  const float rstd = rsqrtf(var + 1e-5f);
  float4* orow = (float4*)(out + (size_t)row * DDIM);
#pragma unroll
  for (int t = 0; t < 4; t++) {
    const int fi = t * 64 + lane;
    float4 gm = ((const float4*)gamma)[fi];
    float4 bt = ((const float4*)beta)[fi];
    float4 o;
    o.x = (z[t].x - mu) * rstd * gm.x + bt.x;
    o.y = (z[t].y - mu) * rstd * gm.y + bt.y;
    o.z = (z[t].z - mu) * rstd * gm.z + bt.z;
    o.w = (z[t].w - mu) * rstd * gm.w + bt.w;
    orow[fi] = o;
  }
}

// ---------------- residual gate + LayerNorm in place (atomic fallback) ----------------
__global__ __launch_bounds__(256)
void k_ln(const float* __restrict__ x, const float* __restrict__ gs,
          const float* __restrict__ gamma, const float* __restrict__ beta,
          float* __restrict__ out) {
  const int row = blockIdx.x, tid = threadIdx.x;
  const float g = gs[0];
  const float4* xr = (const float4*)(x + (size_t)row * DDIM);
  float4* orow = (float4*)(out + (size_t)row * DDIM);
  float4 xv = xr[tid];
  float4 av = orow[tid];
  float4 z;
  z.x = xv.x + g * av.x; z.y = xv.y + g * av.y;
  z.z = xv.z + g * av.z; z.w = xv.w + g * av.w;
  float s = z.x + z.y + z.z + z.w;
  float ss = z.x * z.x + z.y * z.y + z.z * z.z + z.w * z.w;
#pragma unroll
  for (int m = 1; m < 64; m <<= 1) {
    s += __shfl_xor(s, m);
    ss += __shfl_xor(ss, m);
  }
  __shared__ float sh[8];
  if ((tid & 63) == 0) {
    sh[(tid >> 6) * 2] = s;
    sh[(tid >> 6) * 2 + 1] = ss;
  }
  __syncthreads();
  s = sh[0] + sh[2] + sh[4] + sh[6];
  ss = sh[1] + sh[3] + sh[5] + sh[7];
  const float mu = s * (1.0f / 1024.0f);
  const float var = ss * (1.0f / 1024.0f) - mu * mu;
  const float rstd = rsqrtf(var + 1e-5f);
  float4 gm = ((const float4*)gamma)[tid];
  float4 bt = ((const float4*)beta)[tid];
  float4 o;
  o.x = (z.x - mu) * rstd * gm.x + bt.x;
  o.y = (z.y - mu) * rstd * gm.y + bt.y;
  o.z = (z.z - mu) * rstd * gm.z + bt.z;
  o.w = (z.w - mu) * rstd * gm.w + bt.w;
  orow[tid] = o;
}

extern "C" void kernel_launch(void* const* d_in, const int* in_sizes, int n_in,
                              void* d_out, int out_size, void* d_ws, size_t ws_size,
                              hipStream_t stream) {
  const float* x = (const float*)d_in[0];
  const float* Wr = (const float*)d_in[1];
  const float* br = (const float*)d_in[2];
  const float* W1 = (const float*)d_in[3];
  const float* b1 = (const float*)d_in[4];
  const float* W2 = (const float*)d_in[5];
  const float* b2 = (const float*)d_in[6];
  const float* gs = (const float*)d_in[7];
  const float* gamma = (const float*)d_in[8];
  const float* beta = (const float*)d_in[9];
  float* out = (float*)d_out;

  char* ws = (char*)d_ws;
  size_t off = 0;
  auto alloc = [&](size_t bytes) -> void* {
    void* p = ws + off;
    off += (bytes + 255) / 256 * 256;
    return p;
  };
  u16* xb = (u16*)alloc((size_t)NTOK * DDIM * 2);           // 64 MiB
  u16* W1T = (u16*)alloc((size_t)NEXP * HDIM * DDIM * 2);   // 64 MiB
  u16* W2T = (u16*)alloc((size_t)NEXP * HDIM * DDIM * 2);   // 64 MiB
  int* tokPack = (int*)alloc((size_t)NTOK * 4);
  float* tokW = (float*)alloc((size_t)NTOK * 4);
  int* slotTok = (int*)alloc((size_t)MAXSLOTS * 4);
  float* slotW = (float*)alloc((size_t)MAXSLOTS * 4);
  int* sched = (int*)alloc(128 * 4);
  size_t offFixed = off;

  // ybuf path: dedicated [2][NTOK][DDIM] bf16 (128 MiB) + chunked Hbuf.
  // CH=16384 makes up grid = 1024 wgs (exactly 4 dispatch-waves at 1 block/CU)
  // and dn grid = 256 wgs (exactly 1 wave) -- zero dispatch-wave padding.
  u16* ybuf = (u16*)alloc((size_t)2 * NTOK * DDIM * 2);
  long long chv = ws_size > off ? (long long)((ws_size - off) / ((size_t)HDIM * 2)) : 0;
  int CHmax = (int)((chv / 256) * 256);
  if (CHmax > MAXSLOTS) CHmax = MAXSLOTS;
  bool yb = (CHmax >= 256);
  int CH;
  if (yb) {
    CH = 16384;
    if (CH > CHmax) {  // tight workspace: fall back to balanced chunks
      int nch0 = (MAXSLOTS + CHmax - 1) / CHmax;
      CH = (((MAXSLOTS + nch0 - 1) / nch0) + 255) / 256 * 256;
      if (CH > CHmax) CH = CHmax;
    }
  } else {
    off = offFixed;
    ybuf = nullptr;
    chv = ws_size > off ? (long long)((ws_size - off) / ((size_t)HDIM * 2)) : 0;
    CH = (int)((chv / 256) * 256);
    if (CH > MAXSLOTS) CH = MAXSLOTS;
    if (CH < 256) CH = 256;
  }
  u16* Hbuf = (u16*)alloc((size_t)CH * HDIM * 2);
  int nch = (MAXSLOTS + CH - 1) / CH;

  if (!yb) hipMemsetAsync(d_out, 0, (size_t)out_size * 4, stream);
  hipMemsetAsync(slotTok, 0xFF, (size_t)MAXSLOTS * 4, stream);
  hipMemsetAsync(slotW, 0, (size_t)((char*)sched + 512 - (char*)slotW), stream);

  k_cvt_x<<<2048, 256, 0, stream>>>(x, xb, NTOK * DDIM / 4);
  k_transpose<<<NEXP * (DDIM / 64) * (HDIM / 64), 256, 0, stream>>>(W1, W1T, DDIM, HDIM);
  k_transpose<<<NEXP * (HDIM / 64) * (DDIM / 64), 256, 0, stream>>>(W2, W2T, HDIM, DDIM);
  k_router<<<NTOK / 64, 256, 0, stream>>>(x, Wr, br, tokPack, tokW, sched);
  k_sched<<<1, 64, 0, stream>>>(sched);
  k_scatter<<<NTOK / 256, 256, 0, stream>>>(tokPack, tokW, sched, slotTok, slotW);
  for (int c = 0; c < nch; c++) {
    k_gemm_up<<<(CH / BM) * (HDIM / BN), 512, 0, stream>>>(
        xb, W1T, b1, slotTok, slotW, sched, Hbuf, out, c * CH);
    if (yb) {
      k_gemm_dn_y<<<(CH / BM) * (DDIM / BN), 512, 0, stream>>>(
          Hbuf, W2T, b2, slotTok, slotW, sched, ybuf, out, c * CH);
    } else {
      k_gemm_dn_a<<<(CH / BM) * (DDIM / BN), 512, 0, stream>>>(
          Hbuf, W2T, b2, slotTok, slotW, sched, Hbuf, out, c * CH);
    }
  }
  if (yb) {
    k_ln_gather<<<NTOK / 4, 256, 0, stream>>>(x, ybuf, tokW, gs, gamma, beta, out);
  } else {
    k_ln<<<NTOK, 256, 0, stream>>>(x, gs, gamma, beta, out);
  }
}